// Round 1
// baseline (308.057 us; speedup 1.0000x reference)
//
#include <hip/hip_runtime.h>
#include <math.h>

#define B_ 2
#define T_ 128
#define D_ 1024
#define H_ 8
#define R_ 8
#define NPROJ 2176  // cols: [0,512)=Q [512,1024)=K [1024,1536)=V [1536,1600)=beta [1600,1664)=tg [1664,2176)=gate

// ---------------- Kernel 1: per-(h,r) spectral parameters ----------------
__global__ void params_kernel(const float* __restrict__ mode_logits,
                              const float* __restrict__ log_decay,
                              const float* __restrict__ ols,
                              float* __restrict__ cosw, float* __restrict__ sinw,
                              float* __restrict__ rho, float* __restrict__ modew) {
    int t = threadIdx.x;
    if (t >= 64) return;
    int h = t >> 3;
    // rho = exp(-softplus(ld)) = sigmoid(-ld)
    float ld = log_decay[t];
    rho[t] = 1.0f / (1.0f + expf(ld));
    // softmax over R within row h
    float m = -1e30f;
    for (int i = 0; i < 8; i++) m = fmaxf(m, mode_logits[h * 8 + i]);
    float s = 0.0f;
    for (int i = 0; i < 8; i++) s += expf(mode_logits[h * 8 + i] - m);
    modew[t] = expf(mode_logits[t] - m) / s;
    // omega_full[k] = exp(ols[h,r]) * 10000^{-(2*(k>>1))/64}, repeat_interleave by 2
    float osc = expf(ols[t]);
    float lg = logf(10000.0f);
    for (int k = 0; k < 64; k++) {
        int p = k >> 1;
        float invf = expf(-((float)(2 * p) / 64.0f) * lg);
        float w = osc * invf;
        cosw[t * 64 + k] = cosf(w);
        sinw[t * 64 + k] = sinf(w);
    }
}

// ---------------- Kernel 2: projection GEMM (fp32, 64x64 tiles) ----------------
// x[256,1024] @ {Wq,Wk,Wv,Wb,Wtg,Wg} -> proj[256,2176]; sigmoid on cols >= 1536
__global__ void proj_gemm(const float* __restrict__ x,
                          const float* __restrict__ Wq, const float* __restrict__ Wk,
                          const float* __restrict__ Wv, const float* __restrict__ Wb,
                          const float* __restrict__ Wtg, const float* __restrict__ Wg,
                          float* __restrict__ proj) {
    __shared__ float As[16][65];
    __shared__ float Bs[16][65];
    const int n0 = blockIdx.x * 64, m0 = blockIdx.y * 64;
    const int tid = threadIdx.x;
    const int tx = tid & 15, ty = tid >> 4;
    // segment select: boundaries are all multiples of 64, so uniform per block
    const float* Bp; int coff, ldb;
    if (n0 < 512)       { Bp = Wq;  coff = 0;    ldb = 512; }
    else if (n0 < 1024) { Bp = Wk;  coff = 512;  ldb = 512; }
    else if (n0 < 1536) { Bp = Wv;  coff = 1024; ldb = 512; }
    else if (n0 < 1600) { Bp = Wb;  coff = 1536; ldb = 64; }
    else if (n0 < 1664) { Bp = Wtg; coff = 1600; ldb = 64; }
    else                { Bp = Wg;  coff = 1664; ldb = 512; }
    float acc[4][4] = {};
    for (int k0 = 0; k0 < 1024; k0 += 16) {
        #pragma unroll
        for (int it = 0; it < 4; it++) {
            int mm = (tid >> 4) + 16 * it, kk = tid & 15;
            As[kk][mm] = x[(m0 + mm) * 1024 + k0 + kk];
        }
        #pragma unroll
        for (int it = 0; it < 4; it++) {
            int nn = tid & 63, kk = (tid >> 6) + 4 * it;
            Bs[kk][nn] = Bp[(k0 + kk) * ldb + (n0 - coff) + nn];
        }
        __syncthreads();
        #pragma unroll
        for (int kk = 0; kk < 16; kk++) {
            float a[4], b[4];
            #pragma unroll
            for (int i = 0; i < 4; i++) a[i] = As[kk][ty + 16 * i];
            #pragma unroll
            for (int j = 0; j < 4; j++) b[j] = Bs[kk][tx + 16 * j];
            #pragma unroll
            for (int i = 0; i < 4; i++)
                #pragma unroll
                for (int j = 0; j < 4; j++) acc[i][j] += a[i] * b[j];
        }
        __syncthreads();
    }
    const bool sig = (n0 >= 1536);
    #pragma unroll
    for (int i = 0; i < 4; i++)
        #pragma unroll
        for (int j = 0; j < 4; j++) {
            float vv = acc[i][j];
            if (sig) vv = 1.0f / (1.0f + expf(-vv));
            proj[(m0 + ty + 16 * i) * NPROJ + n0 + tx + 16 * j] = vv;
        }
}

// ---------------- Kernel 3: sequential scan ----------------
// grid = B*H*R = 128 blocks; block = 256 threads; thread = (v = tid>>2, kq = tid&3)
// state rows are independent per v; k-dim (64) split across 4 lanes of 16.
__global__ void scan_kernel(const float* __restrict__ proj,
                            const float* __restrict__ cosw, const float* __restrict__ sinw,
                            const float* __restrict__ rho, const float* __restrict__ modew,
                            float* __restrict__ readbuf) {
    const int bi = blockIdx.x;
    const int b = bi >> 6, hr = bi & 63;
    const int h = hr >> 3, r = hr & 7;
    const int tid = threadIdx.x;
    const int v = tid >> 2, kq = tid & 3, k0 = kq * 16;

    float cw[16], sw[16];
    #pragma unroll
    for (int j = 0; j < 16; j++) {
        cw[j] = cosw[hr * 64 + k0 + j];
        sw[j] = sinw[hr * 64 + k0 + j];
    }
    const float rho_hr = rho[hr];
    const float mw = modew[hr];
    float sr[16] = {}, si[16] = {};

    for (int t = 0; t < T_; t++) {
        const float* base = proj + (size_t)(b * T_ + t) * NPROJ;
        float kv[16], qv[16];
        const float4* kp = (const float4*)(base + 512 + h * 64 + k0);
        const float4* qp = (const float4*)(base + h * 64 + k0);
        #pragma unroll
        for (int jj = 0; jj < 4; jj++) {
            float4 f = kp[jj];
            kv[4 * jj] = f.x; kv[4 * jj + 1] = f.y; kv[4 * jj + 2] = f.z; kv[4 * jj + 3] = f.w;
            float4 g = qp[jj];
            qv[4 * jj] = g.x; qv[4 * jj + 1] = g.y; qv[4 * jj + 2] = g.z; qv[4 * jj + 3] = g.w;
        }
        const float vval = base[1024 + h * 64 + v];
        const float beta = base[1536 + h * 8 + r];
        const float tg   = base[1600 + h * 8 + r];
        const float decay = tg * rho_hr;

        float pp = 0.0f;
        #pragma unroll
        for (int j = 0; j < 16; j++) {
            float ro = sr[j], io = si[j];
            float rr = decay * (cw[j] * ro - sw[j] * io);
            float ii = decay * (sw[j] * ro + cw[j] * io);
            sr[j] = rr; si[j] = ii;
            pp += rr * kv[j];
        }
        pp += __shfl_xor(pp, 1);
        pp += __shfl_xor(pp, 2);
        const float sc = beta * (vval - pp);

        float rp = 0.0f;
        #pragma unroll
        for (int j = 0; j < 16; j++) {
            sr[j] += sc * kv[j];
            rp += sr[j] * qv[j];
        }
        rp += __shfl_xor(rp, 1);
        rp += __shfl_xor(rp, 2);

        if (kq == 0) {
            readbuf[((size_t)bi * T_ + t) * 64 + v] = mw * rp;
        }
    }
}

// ---------------- Kernel 4a: sum over R + gate ----------------
__global__ void combine_kernel(const float* __restrict__ readbuf,
                               const float* __restrict__ proj,
                               float* __restrict__ Acomb) {
    int idx = blockIdx.x * 256 + threadIdx.x;  // 256*512 = 131072 total
    if (idx >= 256 * 512) return;
    int bt = idx >> 9, c = idx & 511;
    int b = bt >> 7, t = bt & 127;
    int h = c >> 6, v = c & 63;
    float s = 0.0f;
    #pragma unroll
    for (int r = 0; r < 8; r++)
        s += readbuf[((size_t)(b * 64 + h * 8 + r) * 128 + t) * 64 + v];
    float gate = proj[bt * NPROJ + 1664 + c];
    Acomb[idx] = gate * s;
}

// ---------------- Kernel 4b: output GEMM ----------------
// A[256,512] @ Wo[512,1024] -> out[256,1024]
__global__ void out_gemm(const float* __restrict__ A, const float* __restrict__ Wo,
                         float* __restrict__ C) {
    __shared__ float As[16][65];
    __shared__ float Bs[16][65];
    const int n0 = blockIdx.x * 64, m0 = blockIdx.y * 64;
    const int tid = threadIdx.x;
    const int tx = tid & 15, ty = tid >> 4;
    float acc[4][4] = {};
    for (int k0 = 0; k0 < 512; k0 += 16) {
        #pragma unroll
        for (int it = 0; it < 4; it++) {
            int mm = (tid >> 4) + 16 * it, kk = tid & 15;
            As[kk][mm] = A[(m0 + mm) * 512 + k0 + kk];
        }
        #pragma unroll
        for (int it = 0; it < 4; it++) {
            int nn = tid & 63, kk = (tid >> 6) + 4 * it;
            Bs[kk][nn] = Wo[(k0 + kk) * 1024 + n0 + nn];
        }
        __syncthreads();
        #pragma unroll
        for (int kk = 0; kk < 16; kk++) {
            float a[4], b[4];
            #pragma unroll
            for (int i = 0; i < 4; i++) a[i] = As[kk][ty + 16 * i];
            #pragma unroll
            for (int j = 0; j < 4; j++) b[j] = Bs[kk][tx + 16 * j];
            #pragma unroll
            for (int i = 0; i < 4; i++)
                #pragma unroll
                for (int j = 0; j < 4; j++) acc[i][j] += a[i] * b[j];
        }
        __syncthreads();
    }
    #pragma unroll
    for (int i = 0; i < 4; i++)
        #pragma unroll
        for (int j = 0; j < 4; j++)
            C[(m0 + ty + 16 * i) * 1024 + n0 + tx + 16 * j] = acc[i][j];
}

extern "C" void kernel_launch(void* const* d_in, const int* in_sizes, int n_in,
                              void* d_out, int out_size, void* d_ws, size_t ws_size,
                              hipStream_t stream) {
    const float* x   = (const float*)d_in[0];
    const float* Wq  = (const float*)d_in[1];
    const float* Wk  = (const float*)d_in[2];
    const float* Wv  = (const float*)d_in[3];
    const float* Wb  = (const float*)d_in[4];
    const float* Wtg = (const float*)d_in[5];
    const float* ml  = (const float*)d_in[6];
    const float* ldc = (const float*)d_in[7];
    const float* ols = (const float*)d_in[8];
    const float* Wg  = (const float*)d_in[9];
    const float* Wo  = (const float*)d_in[10];
    float* out = (float*)d_out;

    float* ws = (float*)d_ws;
    float* proj    = ws;                       // 256*2176 = 557056
    float* cosw    = proj + 256 * NPROJ;       // 4096
    float* sinw    = cosw + 4096;              // 4096
    float* rho     = sinw + 4096;              // 64
    float* modew   = rho + 64;                 // 64
    float* readbuf = modew + 64;               // 2*8*8*128*64 = 1048576
    float* Acomb   = readbuf + 1048576;        // 131072

    params_kernel<<<1, 64, 0, stream>>>(ml, ldc, ols, cosw, sinw, rho, modew);
    proj_gemm<<<dim3(34, 4), 256, 0, stream>>>(x, Wq, Wk, Wv, Wb, Wtg, Wg, proj);
    scan_kernel<<<128, 256, 0, stream>>>(proj, cosw, sinw, rho, modew, readbuf);
    combine_kernel<<<512, 256, 0, stream>>>(readbuf, proj, Acomb);
    out_gemm<<<dim3(16, 4), 256, 0, stream>>>(Acomb, Wo, out);
}

// Round 2
// 294.047 us; speedup vs baseline: 1.0476x; 1.0476x over previous
//
#include <hip/hip_runtime.h>
#include <math.h>

#define B_ 2
#define T_ 128
#define D_ 1024
#define H_ 8
#define R_ 8
#define NPROJ 2176  // cols: [0,512)=Q [512,1024)=K [1024,1536)=V [1536,1600)=beta [1600,1664)=tg [1664,2176)=gate

// ---------------- Kernel 1: per-(h,r) spectral parameters ----------------
__global__ void params_kernel(const float* __restrict__ mode_logits,
                              const float* __restrict__ log_decay,
                              const float* __restrict__ ols,
                              float* __restrict__ cosw, float* __restrict__ sinw,
                              float* __restrict__ rho, float* __restrict__ modew) {
    int t = threadIdx.x;
    if (t >= 64) return;
    int h = t >> 3;
    float ld = log_decay[t];
    rho[t] = 1.0f / (1.0f + expf(ld));  // exp(-softplus(ld)) == sigmoid(-ld)
    float m = -1e30f;
    for (int i = 0; i < 8; i++) m = fmaxf(m, mode_logits[h * 8 + i]);
    float s = 0.0f;
    for (int i = 0; i < 8; i++) s += expf(mode_logits[h * 8 + i] - m);
    modew[t] = expf(mode_logits[t] - m) / s;
    float osc = expf(ols[t]);
    float lg = logf(10000.0f);
    for (int k = 0; k < 64; k++) {
        int p = k >> 1;
        float invf = expf(-((float)(2 * p) / 64.0f) * lg);
        float w = osc * invf;
        cosw[t * 64 + k] = cosf(w);
        sinw[t * 64 + k] = sinf(w);
    }
}

// ---------------- Kernel 2: projection GEMM (fp32, 64x64 tiles, b128 LDS) ----------------
// thread tile: rows m0+ty*4..+3, cols n0+tx*4..+3 (contiguous -> float4 LDS reads/stores)
__global__ __launch_bounds__(256) void proj_gemm(const float* __restrict__ x,
                          const float* __restrict__ Wq, const float* __restrict__ Wk,
                          const float* __restrict__ Wv, const float* __restrict__ Wb,
                          const float* __restrict__ Wtg, const float* __restrict__ Wg,
                          float* __restrict__ proj) {
    __shared__ float As[16][68];   // row pad to 68 floats: 16B-aligned rows, 2-way max bank alias
    __shared__ float Bs[16][68];
    const int n0 = blockIdx.x * 64, m0 = blockIdx.y * 64;
    const int tid = threadIdx.x;
    const int tx = tid & 15, ty = tid >> 4;
    const float* Bp; int coff, ldb;
    if (n0 < 512)       { Bp = Wq;  coff = 0;    ldb = 512; }
    else if (n0 < 1024) { Bp = Wk;  coff = 512;  ldb = 512; }
    else if (n0 < 1536) { Bp = Wv;  coff = 1024; ldb = 512; }
    else if (n0 < 1600) { Bp = Wb;  coff = 1536; ldb = 64; }
    else if (n0 < 1664) { Bp = Wtg; coff = 1600; ldb = 64; }
    else                { Bp = Wg;  coff = 1664; ldb = 512; }
    float acc[4][4] = {};
    const int mm = tid >> 2, kq2 = tid & 3;   // A staging: row mm, k-quad kq2
    const int kb = tid >> 4, nq = tid & 15;   // B staging: k-row kb, col-quad nq
    for (int k0 = 0; k0 < 1024; k0 += 16) {
        float4 xa = *(const float4*)&x[(m0 + mm) * 1024 + k0 + kq2 * 4];
        As[kq2 * 4 + 0][mm] = xa.x; As[kq2 * 4 + 1][mm] = xa.y;
        As[kq2 * 4 + 2][mm] = xa.z; As[kq2 * 4 + 3][mm] = xa.w;
        float4 bb = *(const float4*)&Bp[(k0 + kb) * ldb + (n0 - coff) + nq * 4];
        *(float4*)&Bs[kb][nq * 4] = bb;
        __syncthreads();
        #pragma unroll
        for (int kk = 0; kk < 16; kk++) {
            float4 a4 = *(const float4*)&As[kk][ty * 4];
            float4 b4 = *(const float4*)&Bs[kk][tx * 4];
            float a[4] = {a4.x, a4.y, a4.z, a4.w};
            float bv[4] = {b4.x, b4.y, b4.z, b4.w};
            #pragma unroll
            for (int i = 0; i < 4; i++)
                #pragma unroll
                for (int j = 0; j < 4; j++) acc[i][j] += a[i] * bv[j];
        }
        __syncthreads();
    }
    const bool sig = (n0 >= 1536);
    #pragma unroll
    for (int i = 0; i < 4; i++) {
        float4 o;
        float* oo = (float*)&o;
        #pragma unroll
        for (int j = 0; j < 4; j++) {
            float vv = acc[i][j];
            if (sig) vv = 1.0f / (1.0f + expf(-vv));
            oo[j] = vv;
        }
        *(float4*)&proj[(m0 + ty * 4 + i) * NPROJ + n0 + tx * 4] = o;
    }
}

// ---------------- Kernel 3: sequential scan (register-pipelined) ----------------
// grid = B*H*R = 128 blocks; block = 256 threads; thread = (v = tid>>2, kq = tid&3)
// t+1 loads prefetched into regs during step t; dot products tree-reduced.
__global__ __launch_bounds__(256) void scan_kernel(const float* __restrict__ proj,
                            const float* __restrict__ cosw, const float* __restrict__ sinw,
                            const float* __restrict__ rho, const float* __restrict__ modew,
                            float* __restrict__ readbuf) {
    const int bi = blockIdx.x;
    const int b = bi >> 6, hr = bi & 63;
    const int h = hr >> 3, r = hr & 7;
    const int tid = threadIdx.x;
    const int v = tid >> 2, kq = tid & 3, k0 = kq * 16;

    float cw[16], sw[16];
    #pragma unroll
    for (int j = 0; j < 16; j++) {
        cw[j] = cosw[hr * 64 + k0 + j];
        sw[j] = sinw[hr * 64 + k0 + j];
    }
    const float rho_hr = rho[hr];
    const float mw = modew[hr];
    float sr[16] = {}, si[16] = {};

    const float* pb = proj + (size_t)b * T_ * NPROJ;
    const int qoff = h * 64 + k0;
    const int koff = 512 + h * 64 + k0;
    const int voff = 1024 + h * 64 + v;
    const int boff = 1536 + h * 8 + r;
    const int goff = 1600 + h * 8 + r;

    float kv[16], qv[16], vval, bt, gt;
    {
        const float* row = pb;
        #pragma unroll
        for (int jj = 0; jj < 4; jj++) {
            float4 f = *(const float4*)(row + koff + jj * 4);
            kv[4 * jj] = f.x; kv[4 * jj + 1] = f.y; kv[4 * jj + 2] = f.z; kv[4 * jj + 3] = f.w;
            float4 g = *(const float4*)(row + qoff + jj * 4);
            qv[4 * jj] = g.x; qv[4 * jj + 1] = g.y; qv[4 * jj + 2] = g.z; qv[4 * jj + 3] = g.w;
        }
        vval = row[voff]; bt = row[boff]; gt = row[goff];
    }
    float* outp = readbuf + (size_t)bi * T_ * 64 + v;

    for (int t = 0; t < T_; t++) {
        // --- prefetch t+1 (addresses independent of state; compiler hoists loads early) ---
        const int tn = (t + 1 < T_) ? (t + 1) : t;
        const float* row = pb + (size_t)tn * NPROJ;
        float nk[16], nq[16];
        #pragma unroll
        for (int jj = 0; jj < 4; jj++) {
            float4 f = *(const float4*)(row + koff + jj * 4);
            nk[4 * jj] = f.x; nk[4 * jj + 1] = f.y; nk[4 * jj + 2] = f.z; nk[4 * jj + 3] = f.w;
            float4 g = *(const float4*)(row + qoff + jj * 4);
            nq[4 * jj] = g.x; nq[4 * jj + 1] = g.y; nq[4 * jj + 2] = g.z; nq[4 * jj + 3] = g.w;
        }
        const float nvv = row[voff], nbt = row[boff], ngt = row[goff];

        // --- rotate + predict (tree-reduced dot) ---
        const float decay = gt * rho_hr;
        float rr[16], pr[16];
        #pragma unroll
        for (int j = 0; j < 16; j++) {
            const float ro = sr[j], io = si[j];
            const float ar = cw[j] * ro - sw[j] * io;
            const float ai = sw[j] * ro + cw[j] * io;
            const float rrj = decay * ar;
            rr[j] = rrj;
            si[j] = decay * ai;
            pr[j] = rrj * kv[j];
        }
        #pragma unroll
        for (int st = 8; st >= 1; st >>= 1)
            #pragma unroll
            for (int j = 0; j < st; j++) pr[j] += pr[j + st];
        float pp = pr[0];
        pp += __shfl_xor(pp, 1);
        pp += __shfl_xor(pp, 2);
        const float sc = bt * (vval - pp);

        // --- delta write + read (read path off the state critical chain) ---
        float rp2[16];
        #pragma unroll
        for (int j = 0; j < 16; j++) {
            const float s = rr[j] + sc * kv[j];
            sr[j] = s;
            rp2[j] = s * qv[j];
        }
        #pragma unroll
        for (int st = 8; st >= 1; st >>= 1)
            #pragma unroll
            for (int j = 0; j < st; j++) rp2[j] += rp2[j + st];
        float rp = rp2[0];
        rp += __shfl_xor(rp, 1);
        rp += __shfl_xor(rp, 2);
        if (kq == 0) outp[(size_t)t * 64] = mw * rp;

        // --- rotate prefetched regs in ---
        #pragma unroll
        for (int j = 0; j < 16; j++) { kv[j] = nk[j]; qv[j] = nq[j]; }
        vval = nvv; bt = nbt; gt = ngt;
    }
}

// ---------------- Kernel 4a: sum over R + gate ----------------
__global__ void combine_kernel(const float* __restrict__ readbuf,
                               const float* __restrict__ proj,
                               float* __restrict__ Acomb) {
    int idx = blockIdx.x * 256 + threadIdx.x;  // 256*512 = 131072 total
    if (idx >= 256 * 512) return;
    int bt = idx >> 9, c = idx & 511;
    int b = bt >> 7, t = bt & 127;
    int h = c >> 6, v = c & 63;
    float s = 0.0f;
    #pragma unroll
    for (int r = 0; r < 8; r++)
        s += readbuf[((size_t)(b * 64 + h * 8 + r) * 128 + t) * 64 + v];
    float gate = proj[bt * NPROJ + 1664 + c];
    Acomb[idx] = gate * s;
}

// ---------------- Kernel 4b: output GEMM (fp32, b128 LDS) ----------------
__global__ __launch_bounds__(256) void out_gemm(const float* __restrict__ A, const float* __restrict__ Wo,
                         float* __restrict__ C) {
    __shared__ float As[16][68];
    __shared__ float Bs[16][68];
    const int n0 = blockIdx.x * 64, m0 = blockIdx.y * 64;
    const int tid = threadIdx.x;
    const int tx = tid & 15, ty = tid >> 4;
    float acc[4][4] = {};
    const int mm = tid >> 2, kq2 = tid & 3;
    const int kb = tid >> 4, nq = tid & 15;
    for (int k0 = 0; k0 < 512; k0 += 16) {
        float4 xa = *(const float4*)&A[(m0 + mm) * 512 + k0 + kq2 * 4];
        As[kq2 * 4 + 0][mm] = xa.x; As[kq2 * 4 + 1][mm] = xa.y;
        As[kq2 * 4 + 2][mm] = xa.z; As[kq2 * 4 + 3][mm] = xa.w;
        float4 bb = *(const float4*)&Wo[(k0 + kb) * 1024 + n0 + nq * 4];
        *(float4*)&Bs[kb][nq * 4] = bb;
        __syncthreads();
        #pragma unroll
        for (int kk = 0; kk < 16; kk++) {
            float4 a4 = *(const float4*)&As[kk][ty * 4];
            float4 b4 = *(const float4*)&Bs[kk][tx * 4];
            float a[4] = {a4.x, a4.y, a4.z, a4.w};
            float bv[4] = {b4.x, b4.y, b4.z, b4.w};
            #pragma unroll
            for (int i = 0; i < 4; i++)
                #pragma unroll
                for (int j = 0; j < 4; j++) acc[i][j] += a[i] * bv[j];
        }
        __syncthreads();
    }
    #pragma unroll
    for (int i = 0; i < 4; i++) {
        float4 o = make_float4(acc[i][0], acc[i][1], acc[i][2], acc[i][3]);
        *(float4*)&C[(m0 + ty * 4 + i) * 1024 + n0 + tx * 4] = o;
    }
}

extern "C" void kernel_launch(void* const* d_in, const int* in_sizes, int n_in,
                              void* d_out, int out_size, void* d_ws, size_t ws_size,
                              hipStream_t stream) {
    const float* x   = (const float*)d_in[0];
    const float* Wq  = (const float*)d_in[1];
    const float* Wk  = (const float*)d_in[2];
    const float* Wv  = (const float*)d_in[3];
    const float* Wb  = (const float*)d_in[4];
    const float* Wtg = (const float*)d_in[5];
    const float* ml  = (const float*)d_in[6];
    const float* ldc = (const float*)d_in[7];
    const float* ols = (const float*)d_in[8];
    const float* Wg  = (const float*)d_in[9];
    const float* Wo  = (const float*)d_in[10];
    float* out = (float*)d_out;

    float* ws = (float*)d_ws;
    float* proj    = ws;                       // 256*2176 = 557056
    float* cosw    = proj + 256 * NPROJ;       // 4096
    float* sinw    = cosw + 4096;              // 4096
    float* rho     = sinw + 4096;              // 64
    float* modew   = rho + 64;                 // 64
    float* readbuf = modew + 64;               // 2*8*8*128*64 = 1048576
    float* Acomb   = readbuf + 1048576;        // 131072

    params_kernel<<<1, 64, 0, stream>>>(ml, ldc, ols, cosw, sinw, rho, modew);
    proj_gemm<<<dim3(34, 4), 256, 0, stream>>>(x, Wq, Wk, Wv, Wb, Wtg, Wg, proj);
    scan_kernel<<<128, 256, 0, stream>>>(proj, cosw, sinw, rho, modew, readbuf);
    combine_kernel<<<512, 256, 0, stream>>>(readbuf, proj, Acomb);
    out_gemm<<<dim3(16, 4), 256, 0, stream>>>(Acomb, Wo, out);
}

// Round 3
// 190.918 us; speedup vs baseline: 1.6136x; 1.5402x over previous
//
#include <hip/hip_runtime.h>
#include <math.h>

#define B_ 2
#define T_ 128
#define D_ 1024
#define H_ 8
#define R_ 8
#define NPROJ 2176  // cols: [0,512)=Q [512,1024)=K [1024,1536)=V [1536,1600)=beta [1600,1664)=tg [1664,2176)=gate
#define CH 32       // scan chunk (time steps staged in LDS)

// ---------------- Kernel 1: per-(h,r,k) spectral parameters (parallel) ----------------
// grid 16x256 = 4096 threads: one per (hr, k)
__global__ void params_kernel(const float* __restrict__ mode_logits,
                              const float* __restrict__ log_decay,
                              const float* __restrict__ ols,
                              float* __restrict__ cosw, float* __restrict__ sinw,
                              float* __restrict__ rho, float* __restrict__ modew) {
    int idx = blockIdx.x * 256 + threadIdx.x;
    if (idx >= 64 * 64) return;
    int t = idx >> 6;   // hr in [0,64)
    int k = idx & 63;
    int h = t >> 3;
    if (k == 0) {
        float ld = log_decay[t];
        rho[t] = 1.0f / (1.0f + expf(ld));  // exp(-softplus(ld)) == sigmoid(-ld)
        float m = -1e30f;
        for (int i = 0; i < 8; i++) m = fmaxf(m, mode_logits[h * 8 + i]);
        float sum = 0.0f;
        for (int i = 0; i < 8; i++) sum += expf(mode_logits[h * 8 + i] - m);
        modew[t] = expf(mode_logits[t] - m) / sum;
    }
    float osc = expf(ols[t]);
    int p = k >> 1;
    float invf = expf(-((float)(2 * p) / 64.0f) * logf(10000.0f));
    float w = osc * invf;
    cosw[idx] = cosf(w);
    sinw[idx] = sinf(w);
}

// ---------------- Kernel 2: projection GEMM (fp32, 64x64 tiles, reg-dbuf) ----------------
__global__ __launch_bounds__(256) void proj_gemm(const float* __restrict__ x,
                          const float* __restrict__ Wq, const float* __restrict__ Wk,
                          const float* __restrict__ Wv, const float* __restrict__ Wb,
                          const float* __restrict__ Wtg, const float* __restrict__ Wg,
                          float* __restrict__ proj) {
    __shared__ float As[16][68];
    __shared__ float Bs[16][68];
    const int n0 = blockIdx.x * 64, m0 = blockIdx.y * 64;
    const int tid = threadIdx.x;
    const int tx = tid & 15, ty = tid >> 4;
    const float* Bp; int coff, ldb;
    if (n0 < 512)       { Bp = Wq;  coff = 0;    ldb = 512; }
    else if (n0 < 1024) { Bp = Wk;  coff = 512;  ldb = 512; }
    else if (n0 < 1536) { Bp = Wv;  coff = 1024; ldb = 512; }
    else if (n0 < 1600) { Bp = Wb;  coff = 1536; ldb = 64; }
    else if (n0 < 1664) { Bp = Wtg; coff = 1600; ldb = 64; }
    else                { Bp = Wg;  coff = 1664; ldb = 512; }
    float acc[4][4] = {};
    const int mm = tid >> 2, kq2 = tid & 3;
    const int kb = tid >> 4, nq = tid & 15;
    // prologue prefetch
    float4 xa = *(const float4*)&x[(m0 + mm) * 1024 + kq2 * 4];
    float4 wb4 = *(const float4*)&Bp[kb * ldb + (n0 - coff) + nq * 4];
    for (int k0 = 0; k0 < 1024; k0 += 16) {
        As[kq2 * 4 + 0][mm] = xa.x; As[kq2 * 4 + 1][mm] = xa.y;
        As[kq2 * 4 + 2][mm] = xa.z; As[kq2 * 4 + 3][mm] = xa.w;
        *(float4*)&Bs[kb][nq * 4] = wb4;
        __syncthreads();
        if (k0 + 16 < 1024) {
            xa = *(const float4*)&x[(m0 + mm) * 1024 + k0 + 16 + kq2 * 4];
            wb4 = *(const float4*)&Bp[(k0 + 16 + kb) * ldb + (n0 - coff) + nq * 4];
        }
        #pragma unroll
        for (int kk = 0; kk < 16; kk++) {
            float4 a4 = *(const float4*)&As[kk][ty * 4];
            float4 b4 = *(const float4*)&Bs[kk][tx * 4];
            float a[4] = {a4.x, a4.y, a4.z, a4.w};
            float bv[4] = {b4.x, b4.y, b4.z, b4.w};
            #pragma unroll
            for (int i = 0; i < 4; i++)
                #pragma unroll
                for (int j = 0; j < 4; j++) acc[i][j] += a[i] * bv[j];
        }
        __syncthreads();
    }
    const bool sig = (n0 >= 1536);
    #pragma unroll
    for (int i = 0; i < 4; i++) {
        float4 o;
        float* oo = (float*)&o;
        #pragma unroll
        for (int j = 0; j < 4; j++) {
            float vv = acc[i][j];
            if (sig) vv = 1.0f / (1.0f + expf(-vv));
            oo[j] = vv;
        }
        *(float4*)&proj[(m0 + ty * 4 + i) * NPROJ + n0 + tx * 4] = o;
    }
}

// ---------------- DPP butterfly add over the low-3 lane bits ----------------
template<int CTRL>
__device__ __forceinline__ float dpp_add(float x) {
    int xi = __float_as_int(x);
    int yi = __builtin_amdgcn_update_dpp(xi, xi, CTRL, 0xF, 0xF, false);
    return x + __int_as_float(yi);
}

// ---------------- Kernel 3: sequential scan (LDS chunked, DPP reduce) ----------------
// grid = B*H*R*2 = 256 blocks (v split in halves); block = 256 threads.
// thread = (vl = tid>>3 in [0,32), kl = tid&7); k elems kl*8..kl*8+7.
__global__ __launch_bounds__(256, 1) void scan_kernel(const float* __restrict__ proj,
                            const float* __restrict__ cosw, const float* __restrict__ sinw,
                            const float* __restrict__ rho, const float* __restrict__ modew,
                            float* __restrict__ readbuf) {
    __shared__ float qk[2][CH][128];   // per t: [0..63]=q seg, [64..127]=k seg
    __shared__ float vb[2][CH][32];
    __shared__ float bbuf[2][CH];
    __shared__ float gbuf[2][CH];

    const int bi = blockIdx.x;           // 256 blocks
    const int s  = bi & 1;
    const int hr = (bi >> 1) & 63;
    const int b  = bi >> 7;
    const int h  = hr >> 3, r = hr & 7;
    const int tid = threadIdx.x;
    const int vl = tid >> 3;             // 0..31 ; v = s*32+vl
    const int kl = tid & 7;              // 0..7

    float cw[8], sw[8];
    #pragma unroll
    for (int j = 0; j < 8; j++) {
        cw[j] = cosw[hr * 64 + kl * 8 + j];
        sw[j] = sinw[hr * 64 + kl * 8 + j];
    }
    const float rho_hr = rho[hr];
    const float mw = modew[hr];
    float sr[8] = {}, si[8] = {};

    const float* pb = proj + (size_t)b * T_ * NPROJ;
    const int qbase = h * 64;
    const int kbase = 512 + h * 64;
    const int vbase = 1024 + h * 64 + s * 32;
    const int boff  = 1536 + h * 8 + r;
    const int goff  = 1600 + h * 8 + r;

    auto stage = [&](int t0, int nb) {
        #pragma unroll
        for (int rep = 0; rep < 4; rep++) {
            int idx = rep * 256 + tid;
            int t = idx >> 5, sub = idx & 31;
            const float* row = pb + (size_t)(t0 + t) * NPROJ;
            float4 val = *(const float4*)(row + (sub < 16 ? qbase + sub * 4
                                                          : kbase + (sub - 16) * 4));
            *(float4*)&qk[nb][t][sub * 4] = val;
        }
        {
            int t = tid >> 3, sub = tid & 7;
            const float* row = pb + (size_t)(t0 + t) * NPROJ;
            *(float4*)&vb[nb][t][sub * 4] = *(const float4*)(row + vbase + sub * 4);
        }
        if (tid < CH)            bbuf[nb][tid]      = pb[(size_t)(t0 + tid) * NPROJ + boff];
        else if (tid < 2 * CH)   gbuf[nb][tid - CH] = pb[(size_t)(t0 + tid - CH) * NPROJ + goff];
    };

    stage(0, 0);
    __syncthreads();

    float* outp = readbuf + (size_t)(b * 64 + hr) * T_ * 64 + s * 32 + vl;

    for (int c = 0; c < T_ / CH; c++) {
        const int cb = c & 1;
        // load step-0 regs of this chunk
        float kv[8], qv[8], vv, bt, gt;
        {
            float4 k0f = *(const float4*)&qk[cb][0][64 + kl * 8];
            float4 k1f = *(const float4*)&qk[cb][0][64 + kl * 8 + 4];
            float4 q0f = *(const float4*)&qk[cb][0][kl * 8];
            float4 q1f = *(const float4*)&qk[cb][0][kl * 8 + 4];
            kv[0]=k0f.x; kv[1]=k0f.y; kv[2]=k0f.z; kv[3]=k0f.w;
            kv[4]=k1f.x; kv[5]=k1f.y; kv[6]=k1f.z; kv[7]=k1f.w;
            qv[0]=q0f.x; qv[1]=q0f.y; qv[2]=q0f.z; qv[3]=q0f.w;
            qv[4]=q1f.x; qv[5]=q1f.y; qv[6]=q1f.z; qv[7]=q1f.w;
            vv = vb[cb][0][vl]; bt = bbuf[cb][0]; gt = gbuf[cb][0];
        }
        // stage next chunk into other buffer (overlaps this chunk's compute)
        if (c + 1 < T_ / CH) stage((c + 1) * CH, (c + 1) & 1);

        #pragma unroll 4
        for (int t = 0; t < CH; t++) {
            // prefetch step t+1 from LDS
            const int tn = (t + 1 < CH) ? t + 1 : t;
            float nk[8], nq[8];
            float4 k0f = *(const float4*)&qk[cb][tn][64 + kl * 8];
            float4 k1f = *(const float4*)&qk[cb][tn][64 + kl * 8 + 4];
            float4 q0f = *(const float4*)&qk[cb][tn][kl * 8];
            float4 q1f = *(const float4*)&qk[cb][tn][kl * 8 + 4];
            nk[0]=k0f.x; nk[1]=k0f.y; nk[2]=k0f.z; nk[3]=k0f.w;
            nk[4]=k1f.x; nk[5]=k1f.y; nk[6]=k1f.z; nk[7]=k1f.w;
            nq[0]=q0f.x; nq[1]=q0f.y; nq[2]=q0f.z; nq[3]=q0f.w;
            nq[4]=q1f.x; nq[5]=q1f.y; nq[6]=q1f.z; nq[7]=q1f.w;
            const float nvv = vb[cb][tn][vl];
            const float nbt = bbuf[cb][tn];
            const float ngt = gbuf[cb][tn];

            // rotate + three concurrent partial dots
            const float decay = gt * rho_hr;
            float rr[8];
            float pk = 0.0f, pq = 0.0f, kq = 0.0f;
            #pragma unroll
            for (int j = 0; j < 8; j++) {
                const float dc = decay * cw[j], ds = decay * sw[j];
                const float o_r = sr[j], o_i = si[j];
                rr[j] = dc * o_r - ds * o_i;
                si[j] = ds * o_r + dc * o_i;
                pk += rr[j] * kv[j];
                pq += rr[j] * qv[j];
                kq += kv[j] * qv[j];
            }
            // butterfly over 8 k-lanes (low 3 lane bits): xor1, xor2, half-mirror
            pk = dpp_add<0xB1>(pk);  pq = dpp_add<0xB1>(pq);  kq = dpp_add<0xB1>(kq);
            pk = dpp_add<0x4E>(pk);  pq = dpp_add<0x4E>(pq);  kq = dpp_add<0x4E>(kq);
            pk = dpp_add<0x141>(pk); pq = dpp_add<0x141>(pq); kq = dpp_add<0x141>(kq);

            const float sc = bt * (vv - pk);
            #pragma unroll
            for (int j = 0; j < 8; j++) sr[j] = rr[j] + sc * kv[j];
            const float rp = pq + sc * kq;   // = sum(sr_new * q)
            if (kl == 0) outp[(size_t)(c * CH + t) * 64] = mw * rp;

            #pragma unroll
            for (int j = 0; j < 8; j++) { kv[j] = nk[j]; qv[j] = nq[j]; }
            vv = nvv; bt = nbt; gt = ngt;
        }
        __syncthreads();
    }
}

// ---------------- Kernel 4a: sum over R + gate ----------------
__global__ void combine_kernel(const float* __restrict__ readbuf,
                               const float* __restrict__ proj,
                               float* __restrict__ Acomb) {
    int idx = blockIdx.x * 256 + threadIdx.x;  // 256*512 = 131072 total
    if (idx >= 256 * 512) return;
    int bt = idx >> 9, c = idx & 511;
    int b = bt >> 7, t = bt & 127;
    int h = c >> 6, v = c & 63;
    float s = 0.0f;
    #pragma unroll
    for (int r = 0; r < 8; r++)
        s += readbuf[((size_t)(b * 64 + h * 8 + r) * 128 + t) * 64 + v];
    float gate = proj[bt * NPROJ + 1664 + c];
    Acomb[idx] = gate * s;
}

// ---------------- Kernel 4b: output GEMM (fp32, reg-dbuf) ----------------
__global__ __launch_bounds__(256) void out_gemm(const float* __restrict__ A, const float* __restrict__ Wo,
                         float* __restrict__ C) {
    __shared__ float As[16][68];
    __shared__ float Bs[16][68];
    const int n0 = blockIdx.x * 64, m0 = blockIdx.y * 64;
    const int tid = threadIdx.x;
    const int tx = tid & 15, ty = tid >> 4;
    float acc[4][4] = {};
    const int mm = tid >> 2, kq2 = tid & 3;
    const int kb = tid >> 4, nq = tid & 15;
    float4 xa = *(const float4*)&A[(m0 + mm) * 512 + kq2 * 4];
    float4 wb4 = *(const float4*)&Wo[kb * 1024 + n0 + nq * 4];
    for (int k0 = 0; k0 < 512; k0 += 16) {
        As[kq2 * 4 + 0][mm] = xa.x; As[kq2 * 4 + 1][mm] = xa.y;
        As[kq2 * 4 + 2][mm] = xa.z; As[kq2 * 4 + 3][mm] = xa.w;
        *(float4*)&Bs[kb][nq * 4] = wb4;
        __syncthreads();
        if (k0 + 16 < 512) {
            xa = *(const float4*)&A[(m0 + mm) * 512 + k0 + 16 + kq2 * 4];
            wb4 = *(const float4*)&Wo[(k0 + 16 + kb) * 1024 + n0 + nq * 4];
        }
        #pragma unroll
        for (int kk = 0; kk < 16; kk++) {
            float4 a4 = *(const float4*)&As[kk][ty * 4];
            float4 b4 = *(const float4*)&Bs[kk][tx * 4];
            float a[4] = {a4.x, a4.y, a4.z, a4.w};
            float bv[4] = {b4.x, b4.y, b4.z, b4.w};
            #pragma unroll
            for (int i = 0; i < 4; i++)
                #pragma unroll
                for (int j = 0; j < 4; j++) acc[i][j] += a[i] * bv[j];
        }
        __syncthreads();
    }
    #pragma unroll
    for (int i = 0; i < 4; i++) {
        float4 o = make_float4(acc[i][0], acc[i][1], acc[i][2], acc[i][3]);
        *(float4*)&C[(m0 + ty * 4 + i) * 1024 + n0 + tx * 4] = o;
    }
}

extern "C" void kernel_launch(void* const* d_in, const int* in_sizes, int n_in,
                              void* d_out, int out_size, void* d_ws, size_t ws_size,
                              hipStream_t stream) {
    const float* x   = (const float*)d_in[0];
    const float* Wq  = (const float*)d_in[1];
    const float* Wk  = (const float*)d_in[2];
    const float* Wv  = (const float*)d_in[3];
    const float* Wb  = (const float*)d_in[4];
    const float* Wtg = (const float*)d_in[5];
    const float* ml  = (const float*)d_in[6];
    const float* ldc = (const float*)d_in[7];
    const float* ols = (const float*)d_in[8];
    const float* Wg  = (const float*)d_in[9];
    const float* Wo  = (const float*)d_in[10];
    float* out = (float*)d_out;

    float* ws = (float*)d_ws;
    float* proj    = ws;                       // 256*2176 = 557056
    float* cosw    = proj + 256 * NPROJ;       // 4096
    float* sinw    = cosw + 4096;              // 4096
    float* rho     = sinw + 4096;              // 64
    float* modew   = rho + 64;                 // 64
    float* readbuf = modew + 64;               // 2*8*8*128*64 = 1048576
    float* Acomb   = readbuf + 1048576;        // 131072

    params_kernel<<<16, 256, 0, stream>>>(ml, ldc, ols, cosw, sinw, rho, modew);
    proj_gemm<<<dim3(34, 4), 256, 0, stream>>>(x, Wq, Wk, Wv, Wb, Wtg, Wg, proj);
    scan_kernel<<<256, 256, 0, stream>>>(proj, cosw, sinw, rho, modew, readbuf);
    combine_kernel<<<512, 256, 0, stream>>>(readbuf, proj, Acomb);
    out_gemm<<<dim3(16, 4), 256, 0, stream>>>(Acomb, Wo, out);
}

// Round 4
// 146.724 us; speedup vs baseline: 2.0996x; 1.3012x over previous
//
#include <hip/hip_runtime.h>
#include <math.h>

#define T_ 128
#define NPROJ 2176  // cols: [0,512)=Q [512,1024)=K [1024,1536)=V [1536,1600)=beta [1600,1664)=tg [1664,2176)=gate
#define CH 32       // scan chunk

typedef __attribute__((ext_vector_type(8))) short short8;
typedef __attribute__((ext_vector_type(4))) float float4v;

__device__ __forceinline__ ushort f2bf(float x) {
    unsigned u = __float_as_uint(x);
    u += 0x7FFF + ((u >> 16) & 1);   // RNE
    return (ushort)(u >> 16);
}

// ---------------- Kernel 1: prep = params + x->bf16 + W/Wo transpose-convert ----------
// blocks [0,16): params  [16,80): x convert  [80,624): W transpose  [624,752): Wo transpose
__global__ __launch_bounds__(256) void prep_kernel(
    const float* __restrict__ x,
    const float* __restrict__ Wq, const float* __restrict__ Wk,
    const float* __restrict__ Wv, const float* __restrict__ Wb,
    const float* __restrict__ Wtg, const float* __restrict__ Wg,
    const float* __restrict__ Wo,
    const float* __restrict__ mode_logits, const float* __restrict__ log_decay,
    const float* __restrict__ ols,
    float* __restrict__ cosw, float* __restrict__ sinw,
    float* __restrict__ rho, float* __restrict__ modew,
    ushort* __restrict__ xb, ushort* __restrict__ wtb, ushort* __restrict__ wotb)
{
    __shared__ ushort tile[64][68];
    const int blk = blockIdx.x, tid = threadIdx.x;
    if (blk < 16) {
        int idx = blk * 256 + tid;
        if (idx >= 64 * 64) return;
        int t = idx >> 6;   // hr
        int k = idx & 63;
        int h = t >> 3;
        if (k == 0) {
            float ld = log_decay[t];
            rho[t] = 1.0f / (1.0f + expf(ld));  // exp(-softplus) == sigmoid(-x)
            float m = -1e30f;
            for (int i = 0; i < 8; i++) m = fmaxf(m, mode_logits[h * 8 + i]);
            float sum = 0.0f;
            for (int i = 0; i < 8; i++) sum += expf(mode_logits[h * 8 + i] - m);
            modew[t] = expf(mode_logits[t] - m) / sum;
        }
        float osc = expf(ols[t]);
        int p = k >> 1;
        float invf = expf(-((float)(2 * p) / 64.0f) * logf(10000.0f));
        float w = osc * invf;
        cosw[idx] = cosf(w);
        sinw[idx] = sinf(w);
        return;
    }
    if (blk < 80) {   // x convert: 64 blocks x 256 thr x 16 elems = 262144
        int base = (blk - 16) * 4096 + tid * 16;
        float4 f0 = *(const float4*)&x[base];
        float4 f1 = *(const float4*)&x[base + 4];
        float4 f2 = *(const float4*)&x[base + 8];
        float4 f3 = *(const float4*)&x[base + 12];
        short8 o0, o1;
        o0[0]=f2bf(f0.x); o0[1]=f2bf(f0.y); o0[2]=f2bf(f0.z); o0[3]=f2bf(f0.w);
        o0[4]=f2bf(f1.x); o0[5]=f2bf(f1.y); o0[6]=f2bf(f1.z); o0[7]=f2bf(f1.w);
        o1[0]=f2bf(f2.x); o1[1]=f2bf(f2.y); o1[2]=f2bf(f2.z); o1[3]=f2bf(f2.w);
        o1[4]=f2bf(f3.x); o1[5]=f2bf(f3.y); o1[6]=f2bf(f3.z); o1[7]=f2bf(f3.w);
        *(short8*)&xb[base] = o0;
        *(short8*)&xb[base + 8] = o1;
        return;
    }
    // transpose-convert: src fp32 [K][ld] tile (k0,c0) -> dst bf16 [N][ldd] tile (n0,k0)
    const float* src; int ld, c0, n0, k0, ldd; ushort* dst;
    if (blk < 624) {
        int b3 = blk - 80; int nt = b3 >> 4, kt = b3 & 15;
        n0 = nt * 64; k0 = kt * 64;
        if (n0 < 512)       { src = Wq;  c0 = n0;        ld = 512; }
        else if (n0 < 1024) { src = Wk;  c0 = n0 - 512;  ld = 512; }
        else if (n0 < 1536) { src = Wv;  c0 = n0 - 1024; ld = 512; }
        else if (n0 < 1600) { src = Wb;  c0 = n0 - 1536; ld = 64;  }
        else if (n0 < 1664) { src = Wtg; c0 = n0 - 1600; ld = 64;  }
        else                { src = Wg;  c0 = n0 - 1664; ld = 512; }
        dst = wtb; ldd = 1024;
    } else {
        int b4 = blk - 624; int nt = b4 >> 3, kt = b4 & 7;
        n0 = nt * 64; k0 = kt * 64;
        src = Wo; c0 = n0; ld = 1024; dst = wotb; ldd = 512;
    }
    #pragma unroll
    for (int rep = 0; rep < 4; rep++) {
        int k = rep * 16 + (tid >> 4);
        int nc = (tid & 15) * 4;
        float4 f = *(const float4*)&src[(size_t)(k0 + k) * ld + c0 + nc];
        tile[nc + 0][k] = f2bf(f.x);
        tile[nc + 1][k] = f2bf(f.y);
        tile[nc + 2][k] = f2bf(f.z);
        tile[nc + 3][k] = f2bf(f.w);
    }
    __syncthreads();
    #pragma unroll
    for (int rep = 0; rep < 4; rep++) {
        int n = rep * 16 + (tid >> 4);
        int kc = (tid & 15) * 4;
        uint2 u = *(const uint2*)&tile[n][kc];
        *(uint2*)&dst[(size_t)(n0 + n) * ldd + k0 + kc] = u;
    }
}

// ---------------- MFMA GEMM: C[M][ldc-seg] = A[M][K]_bf16 * BT[N][K]_bf16^T ------------
// wg 256 = 4 waves; wg tile 64x64; wave tile 32x32 (2x2 mfma 16x16x32); BK=32, LDS dbuf.
__global__ __launch_bounds__(256, 2) void proj_mfma(const ushort* __restrict__ Ab,
        const ushort* __restrict__ BTb, float* __restrict__ proj)
{
    __shared__ ushort sA[2][64][40];
    __shared__ ushort sB[2][64][40];
    const int n0 = blockIdx.x * 64, m0 = blockIdx.y * 64;
    const int tid = threadIdx.x;
    const int lane = tid & 63, w = tid >> 6;
    const int wm = w & 1, wn = w >> 1;
    const int l16 = lane & 15, quad = lane >> 4;
    const int srow = tid >> 2, skq = (tid & 3) * 8;
    const ushort* Ag = Ab + (size_t)(m0 + srow) * 1024 + skq;
    const ushort* Bg = BTb + (size_t)(n0 + srow) * 1024 + skq;
    short8 ra = *(const short8*)Ag;
    short8 rb = *(const short8*)Bg;
    float4v acc00 = {0,0,0,0}, acc01 = {0,0,0,0}, acc10 = {0,0,0,0}, acc11 = {0,0,0,0};
    for (int kt = 0; kt < 32; kt++) {
        const int cb = kt & 1;
        *(short8*)&sA[cb][srow][skq] = ra;
        *(short8*)&sB[cb][srow][skq] = rb;
        __syncthreads();
        if (kt + 1 < 32) {
            ra = *(const short8*)(Ag + (kt + 1) * 32);
            rb = *(const short8*)(Bg + (kt + 1) * 32);
        }
        short8 a0 = *(const short8*)&sA[cb][wm * 32 + l16][quad * 8];
        short8 a1 = *(const short8*)&sA[cb][wm * 32 + 16 + l16][quad * 8];
        short8 b0 = *(const short8*)&sB[cb][wn * 32 + l16][quad * 8];
        short8 b1 = *(const short8*)&sB[cb][wn * 32 + 16 + l16][quad * 8];
        acc00 = __builtin_amdgcn_mfma_f32_16x16x32_bf16(a0, b0, acc00, 0, 0, 0);
        acc01 = __builtin_amdgcn_mfma_f32_16x16x32_bf16(a0, b1, acc01, 0, 0, 0);
        acc10 = __builtin_amdgcn_mfma_f32_16x16x32_bf16(a1, b0, acc10, 0, 0, 0);
        acc11 = __builtin_amdgcn_mfma_f32_16x16x32_bf16(a1, b1, acc11, 0, 0, 0);
    }
    const bool sig = (n0 >= 1536);
    const int colb = n0 + wn * 32 + l16;
    const int rowb = m0 + wm * 32 + quad * 4;
    #pragma unroll
    for (int r2 = 0; r2 < 4; r2++) {
        float v00 = acc00[r2], v01 = acc01[r2], v10 = acc10[r2], v11 = acc11[r2];
        if (sig) {
            v00 = 1.0f / (1.0f + expf(-v00));
            v01 = 1.0f / (1.0f + expf(-v01));
            v10 = 1.0f / (1.0f + expf(-v10));
            v11 = 1.0f / (1.0f + expf(-v11));
        }
        proj[(size_t)(rowb + r2) * NPROJ + colb] = v00;
        proj[(size_t)(rowb + r2) * NPROJ + colb + 16] = v01;
        proj[(size_t)(rowb + 16 + r2) * NPROJ + colb] = v10;
        proj[(size_t)(rowb + 16 + r2) * NPROJ + colb + 16] = v11;
    }
}

__global__ __launch_bounds__(256, 2) void out_mfma(const ushort* __restrict__ Ab,
        const ushort* __restrict__ BTb, float* __restrict__ C)
{
    __shared__ ushort sA[2][64][40];
    __shared__ ushort sB[2][64][40];
    const int n0 = blockIdx.x * 64, m0 = blockIdx.y * 64;
    const int tid = threadIdx.x;
    const int lane = tid & 63, w = tid >> 6;
    const int wm = w & 1, wn = w >> 1;
    const int l16 = lane & 15, quad = lane >> 4;
    const int srow = tid >> 2, skq = (tid & 3) * 8;
    const ushort* Ag = Ab + (size_t)(m0 + srow) * 512 + skq;
    const ushort* Bg = BTb + (size_t)(n0 + srow) * 512 + skq;
    short8 ra = *(const short8*)Ag;
    short8 rb = *(const short8*)Bg;
    float4v acc00 = {0,0,0,0}, acc01 = {0,0,0,0}, acc10 = {0,0,0,0}, acc11 = {0,0,0,0};
    for (int kt = 0; kt < 16; kt++) {
        const int cb = kt & 1;
        *(short8*)&sA[cb][srow][skq] = ra;
        *(short8*)&sB[cb][srow][skq] = rb;
        __syncthreads();
        if (kt + 1 < 16) {
            ra = *(const short8*)(Ag + (kt + 1) * 32);
            rb = *(const short8*)(Bg + (kt + 1) * 32);
        }
        short8 a0 = *(const short8*)&sA[cb][wm * 32 + l16][quad * 8];
        short8 a1 = *(const short8*)&sA[cb][wm * 32 + 16 + l16][quad * 8];
        short8 b0 = *(const short8*)&sB[cb][wn * 32 + l16][quad * 8];
        short8 b1 = *(const short8*)&sB[cb][wn * 32 + 16 + l16][quad * 8];
        acc00 = __builtin_amdgcn_mfma_f32_16x16x32_bf16(a0, b0, acc00, 0, 0, 0);
        acc01 = __builtin_amdgcn_mfma_f32_16x16x32_bf16(a0, b1, acc01, 0, 0, 0);
        acc10 = __builtin_amdgcn_mfma_f32_16x16x32_bf16(a1, b0, acc10, 0, 0, 0);
        acc11 = __builtin_amdgcn_mfma_f32_16x16x32_bf16(a1, b1, acc11, 0, 0, 0);
    }
    const int colb = n0 + wn * 32 + l16;
    const int rowb = m0 + wm * 32 + quad * 4;
    #pragma unroll
    for (int r2 = 0; r2 < 4; r2++) {
        C[(size_t)(rowb + r2) * 1024 + colb] = acc00[r2];
        C[(size_t)(rowb + r2) * 1024 + colb + 16] = acc01[r2];
        C[(size_t)(rowb + 16 + r2) * 1024 + colb] = acc10[r2];
        C[(size_t)(rowb + 16 + r2) * 1024 + colb + 16] = acc11[r2];
    }
}

// ---------------- DPP butterfly add over low-4 lane bits (16-lane rows) ---------------
template<int CTRL>
__device__ __forceinline__ float dpp_add(float x) {
    int xi = __float_as_int(x);
    int yi = __builtin_amdgcn_update_dpp(xi, xi, CTRL, 0xF, 0xF, false);
    return x + __int_as_float(yi);
}

// ---------------- Kernel 3: scan, v-split S=4 -> 512 blocks (2 blocks/CU) -------------
// block 256 thr: kl = tid&15 (16 k-lanes x 4 elems), vl = tid>>4 (16 v's); v = s*16+vl
__global__ __launch_bounds__(256, 2) void scan_kernel(const float* __restrict__ proj,
        const float* __restrict__ cosw, const float* __restrict__ sinw,
        const float* __restrict__ rho, const float* __restrict__ modew,
        float* __restrict__ readbuf)
{
    __shared__ float qk[2][CH][128];   // per t: [0..63]=q, [64..127]=k
    __shared__ float vb[2][CH][16];
    __shared__ float bbuf[2][CH];
    __shared__ float gbuf[2][CH];

    const int bi = blockIdx.x;          // bi = ((b*64)+hr)*4 + s
    const int s  = bi & 3;
    const int hr = (bi >> 2) & 63;
    const int b  = bi >> 8;
    const int h = hr >> 3, r = hr & 7;
    const int tid = threadIdx.x;
    const int vl = tid >> 4;
    const int kl = tid & 15;

    float cw[4], sw[4];
    #pragma unroll
    for (int j = 0; j < 4; j++) {
        cw[j] = cosw[hr * 64 + kl * 4 + j];
        sw[j] = sinw[hr * 64 + kl * 4 + j];
    }
    const float rho_hr = rho[hr];
    const float mw = modew[hr];
    float sr[4] = {}, si[4] = {};

    const float* pb = proj + (size_t)b * T_ * NPROJ;
    const int qbase = h * 64;
    const int kbase = 512 + h * 64;
    const int vbase = 1024 + h * 64 + s * 16;
    const int boff  = 1536 + h * 8 + r;
    const int goff  = 1600 + h * 8 + r;

    auto stage = [&](int t0, int nb) {
        #pragma unroll
        for (int rep = 0; rep < 4; rep++) {
            int idx = rep * 256 + tid;
            int t = idx >> 5, sub = idx & 31;
            const float* row = pb + (size_t)(t0 + t) * NPROJ;
            float4 val = *(const float4*)(row + (sub < 16 ? qbase + sub * 4
                                                          : kbase + (sub - 16) * 4));
            *(float4*)&qk[nb][t][sub * 4] = val;
        }
        if (tid < 128) {
            int t = tid >> 2, sub = tid & 3;
            const float* row = pb + (size_t)(t0 + t) * NPROJ;
            *(float4*)&vb[nb][t][sub * 4] = *(const float4*)(row + vbase + sub * 4);
        } else if (tid < 160) {
            bbuf[nb][tid - 128] = pb[(size_t)(t0 + tid - 128) * NPROJ + boff];
        } else if (tid < 192) {
            gbuf[nb][tid - 160] = pb[(size_t)(t0 + tid - 160) * NPROJ + goff];
        }
    };

    stage(0, 0);
    __syncthreads();

    float* outp = readbuf + (size_t)(b * 64 + hr) * T_ * 64 + s * 16 + vl;

    for (int c = 0; c < T_ / CH; c++) {
        const int cb = c & 1;
        float kv[4], qv[4], vv, bt, gt;
        {
            float4 kf = *(const float4*)&qk[cb][0][64 + kl * 4];
            float4 qf = *(const float4*)&qk[cb][0][kl * 4];
            kv[0]=kf.x; kv[1]=kf.y; kv[2]=kf.z; kv[3]=kf.w;
            qv[0]=qf.x; qv[1]=qf.y; qv[2]=qf.z; qv[3]=qf.w;
            vv = vb[cb][0][vl]; bt = bbuf[cb][0]; gt = gbuf[cb][0];
        }
        if (c + 1 < T_ / CH) stage((c + 1) * CH, (c + 1) & 1);

        #pragma unroll 4
        for (int t = 0; t < CH; t++) {
            const int tn = (t + 1 < CH) ? t + 1 : t;
            float4 kf = *(const float4*)&qk[cb][tn][64 + kl * 4];
            float4 qf = *(const float4*)&qk[cb][tn][kl * 4];
            const float nvv = vb[cb][tn][vl];
            const float nbt = bbuf[cb][tn];
            const float ngt = gbuf[cb][tn];

            const float decay = gt * rho_hr;
            float rr[4];
            float pk = 0.0f, pq = 0.0f, kq = 0.0f;
            #pragma unroll
            for (int j = 0; j < 4; j++) {
                const float dc = decay * cw[j], ds = decay * sw[j];
                const float o_r = sr[j], o_i = si[j];
                rr[j] = dc * o_r - ds * o_i;
                si[j] = ds * o_r + dc * o_i;
                pk += rr[j] * kv[j];
                pq += rr[j] * qv[j];
                kq += kv[j] * qv[j];
            }
            // butterfly over 16 k-lanes: xor1, xor2, xor4(half-mirror), xor8(mirror)
            pk = dpp_add<0xB1>(pk);  pq = dpp_add<0xB1>(pq);  kq = dpp_add<0xB1>(kq);
            pk = dpp_add<0x4E>(pk);  pq = dpp_add<0x4E>(pq);  kq = dpp_add<0x4E>(kq);
            pk = dpp_add<0x141>(pk); pq = dpp_add<0x141>(pq); kq = dpp_add<0x141>(kq);
            pk = dpp_add<0x140>(pk); pq = dpp_add<0x140>(pq); kq = dpp_add<0x140>(kq);

            const float sc = bt * (vv - pk);
            #pragma unroll
            for (int j = 0; j < 4; j++) sr[j] = rr[j] + sc * kv[j];
            const float rp = pq + sc * kq;   // = sum(sr_new * q) across k
            if (kl == 0) outp[(size_t)(c * CH + t) * 64] = mw * rp;

            kv[0]=kf.x; kv[1]=kf.y; kv[2]=kf.z; kv[3]=kf.w;
            qv[0]=qf.x; qv[1]=qf.y; qv[2]=qf.z; qv[3]=qf.w;
            vv = nvv; bt = nbt; gt = ngt;
        }
        __syncthreads();
    }
}

// ---------------- Kernel 4: sum over R + gate -> bf16 A for out_mfma ------------------
__global__ void combine_kernel(const float* __restrict__ readbuf,
                               const float* __restrict__ proj,
                               ushort* __restrict__ Ab)
{
    int idx = blockIdx.x * 256 + threadIdx.x;  // 131072 total
    if (idx >= 256 * 512) return;
    int bt = idx >> 9, c = idx & 511;
    int b = bt >> 7, t = bt & 127;
    int h = c >> 6, v = c & 63;
    float sacc = 0.0f;
    #pragma unroll
    for (int r = 0; r < 8; r++)
        sacc += readbuf[((size_t)(b * 64 + h * 8 + r) * 128 + t) * 64 + v];
    float gate = proj[(size_t)bt * NPROJ + 1664 + c];
    Ab[idx] = f2bf(gate * sacc);
}

extern "C" void kernel_launch(void* const* d_in, const int* in_sizes, int n_in,
                              void* d_out, int out_size, void* d_ws, size_t ws_size,
                              hipStream_t stream) {
    const float* x   = (const float*)d_in[0];
    const float* Wq  = (const float*)d_in[1];
    const float* Wk  = (const float*)d_in[2];
    const float* Wv  = (const float*)d_in[3];
    const float* Wb  = (const float*)d_in[4];
    const float* Wtg = (const float*)d_in[5];
    const float* ml  = (const float*)d_in[6];
    const float* ldc = (const float*)d_in[7];
    const float* ols = (const float*)d_in[8];
    const float* Wg  = (const float*)d_in[9];
    const float* Wo  = (const float*)d_in[10];
    float* out = (float*)d_out;

    float* ws = (float*)d_ws;
    float* proj    = ws;                        // 557056 f
    float* cosw    = proj + 256 * NPROJ;        // 4096
    float* sinw    = cosw + 4096;               // 4096
    float* rho     = sinw + 4096;               // 64
    float* modew   = rho + 64;                  // 64
    ushort* xb     = (ushort*)(modew + 64);     // 262144 us = 131072 f
    ushort* wotb   = (ushort*)((float*)xb + 131072);    // 524288 us = 262144 f
    ushort* acombb = (ushort*)((float*)wotb + 262144);  // 131072 us = 65536 f
    float* regionR = (float*)acombb + 65536;    // shared: wtb (1114112 f) then readbuf (1048576 f)
    ushort* wtb    = (ushort*)regionR;          // dead after proj_mfma
    float* readbuf = regionR;                   // written by scan afterwards

    prep_kernel<<<752, 256, 0, stream>>>(x, Wq, Wk, Wv, Wb, Wtg, Wg, Wo,
                                         ml, ldc, ols, cosw, sinw, rho, modew,
                                         xb, wtb, wotb);
    proj_mfma<<<dim3(34, 4), 256, 0, stream>>>(xb, wtb, proj);
    scan_kernel<<<512, 256, 0, stream>>>(proj, cosw, sinw, rho, modew, readbuf);
    combine_kernel<<<512, 256, 0, stream>>>(readbuf, proj, acombb);
    out_mfma<<<dim3(16, 4), 256, 0, stream>>>(acombb, wotb, out);
}

// Round 5
// 140.237 us; speedup vs baseline: 2.1967x; 1.0463x over previous
//
#include <hip/hip_runtime.h>
#include <math.h>

#define T_ 128
#define NPROJ 2176  // cols: [0,512)=Q [512,1024)=K [1024,1536)=V [1536,1600)=beta [1600,1664)=tg [1664,2176)=gate
#define CH 32       // scan chunk

typedef __attribute__((ext_vector_type(8))) short short8;
typedef __attribute__((ext_vector_type(4))) float float4v;
typedef __attribute__((ext_vector_type(2))) float float2v;

__device__ __forceinline__ ushort f2bf(float x) {
    unsigned u = __float_as_uint(x);
    u += 0x7FFF + ((u >> 16) & 1);   // RNE
    return (ushort)(u >> 16);
}

// ---------------- Kernel 1: prep = params + x->bf16 + W/Wo transpose + Acomb zero -----
// blocks [0,16): params  [16,80): x convert  [80,624): W transpose  [624,752): Wo
// blocks [752,784): zero Acomb (scan accumulates into it with atomics)
__global__ __launch_bounds__(256) void prep_kernel(
    const float* __restrict__ x,
    const float* __restrict__ Wq, const float* __restrict__ Wk,
    const float* __restrict__ Wv, const float* __restrict__ Wb,
    const float* __restrict__ Wtg, const float* __restrict__ Wg,
    const float* __restrict__ Wo,
    const float* __restrict__ mode_logits, const float* __restrict__ log_decay,
    const float* __restrict__ ols,
    float* __restrict__ cosw, float* __restrict__ sinw,
    float* __restrict__ rho, float* __restrict__ modew,
    ushort* __restrict__ xb, ushort* __restrict__ wtb, ushort* __restrict__ wotb,
    float* __restrict__ Acomb)
{
    __shared__ ushort tile[64][68];
    const int blk = blockIdx.x, tid = threadIdx.x;
    if (blk < 16) {
        int idx = blk * 256 + tid;
        if (idx >= 64 * 64) return;
        int t = idx >> 6;   // hr
        int k = idx & 63;
        int h = t >> 3;
        if (k == 0) {
            float ld = log_decay[t];
            rho[t] = 1.0f / (1.0f + expf(ld));  // exp(-softplus) == sigmoid(-x)
            float m = -1e30f;
            for (int i = 0; i < 8; i++) m = fmaxf(m, mode_logits[h * 8 + i]);
            float sum = 0.0f;
            for (int i = 0; i < 8; i++) sum += expf(mode_logits[h * 8 + i] - m);
            modew[t] = expf(mode_logits[t] - m) / sum;
        }
        float osc = expf(ols[t]);
        int p = k >> 1;
        float invf = expf(-((float)(2 * p) / 64.0f) * logf(10000.0f));
        float w = osc * invf;
        cosw[idx] = cosf(w);
        sinw[idx] = sinf(w);
        return;
    }
    if (blk < 80) {   // x convert
        int base = (blk - 16) * 4096 + tid * 16;
        float4 f0 = *(const float4*)&x[base];
        float4 f1 = *(const float4*)&x[base + 4];
        float4 f2 = *(const float4*)&x[base + 8];
        float4 f3 = *(const float4*)&x[base + 12];
        short8 o0, o1;
        o0[0]=f2bf(f0.x); o0[1]=f2bf(f0.y); o0[2]=f2bf(f0.z); o0[3]=f2bf(f0.w);
        o0[4]=f2bf(f1.x); o0[5]=f2bf(f1.y); o0[6]=f2bf(f1.z); o0[7]=f2bf(f1.w);
        o1[0]=f2bf(f2.x); o1[1]=f2bf(f2.y); o1[2]=f2bf(f2.z); o1[3]=f2bf(f2.w);
        o1[4]=f2bf(f3.x); o1[5]=f2bf(f3.y); o1[6]=f2bf(f3.z); o1[7]=f2bf(f3.w);
        *(short8*)&xb[base] = o0;
        *(short8*)&xb[base + 8] = o1;
        return;
    }
    if (blk >= 752) {  // zero Acomb
        int base = (blk - 752) * 4096 + tid * 16;
        float4 z = make_float4(0.f, 0.f, 0.f, 0.f);
        *(float4*)&Acomb[base] = z;
        *(float4*)&Acomb[base + 4] = z;
        *(float4*)&Acomb[base + 8] = z;
        *(float4*)&Acomb[base + 12] = z;
        return;
    }
    // transpose-convert
    const float* src; int ld, c0, n0, k0, ldd; ushort* dst;
    if (blk < 624) {
        int b3 = blk - 80; int nt = b3 >> 4, kt = b3 & 15;
        n0 = nt * 64; k0 = kt * 64;
        if (n0 < 512)       { src = Wq;  c0 = n0;        ld = 512; }
        else if (n0 < 1024) { src = Wk;  c0 = n0 - 512;  ld = 512; }
        else if (n0 < 1536) { src = Wv;  c0 = n0 - 1024; ld = 512; }
        else if (n0 < 1600) { src = Wb;  c0 = n0 - 1536; ld = 64;  }
        else if (n0 < 1664) { src = Wtg; c0 = n0 - 1600; ld = 64;  }
        else                { src = Wg;  c0 = n0 - 1664; ld = 512; }
        dst = wtb; ldd = 1024;
    } else {
        int b4 = blk - 624; int nt = b4 >> 3, kt = b4 & 7;
        n0 = nt * 64; k0 = kt * 64;
        src = Wo; c0 = n0; ld = 1024; dst = wotb; ldd = 512;
    }
    #pragma unroll
    for (int rep = 0; rep < 4; rep++) {
        int k = rep * 16 + (tid >> 4);
        int nc = (tid & 15) * 4;
        float4 f = *(const float4*)&src[(size_t)(k0 + k) * ld + c0 + nc];
        tile[nc + 0][k] = f2bf(f.x);
        tile[nc + 1][k] = f2bf(f.y);
        tile[nc + 2][k] = f2bf(f.z);
        tile[nc + 3][k] = f2bf(f.w);
    }
    __syncthreads();
    #pragma unroll
    for (int rep = 0; rep < 4; rep++) {
        int n = rep * 16 + (tid >> 4);
        int kc = (tid & 15) * 4;
        uint2 u = *(const uint2*)&tile[n][kc];
        *(uint2*)&dst[(size_t)(n0 + n) * ldd + k0 + kc] = u;
    }
}

// ---------------- Kernel 2: proj MFMA GEMM (unchanged from R4) -------------------------
__global__ __launch_bounds__(256, 2) void proj_mfma(const ushort* __restrict__ Ab,
        const ushort* __restrict__ BTb, float* __restrict__ proj)
{
    __shared__ ushort sA[2][64][40];
    __shared__ ushort sB[2][64][40];
    const int n0 = blockIdx.x * 64, m0 = blockIdx.y * 64;
    const int tid = threadIdx.x;
    const int lane = tid & 63, w = tid >> 6;
    const int wm = w & 1, wn = w >> 1;
    const int l16 = lane & 15, quad = lane >> 4;
    const int srow = tid >> 2, skq = (tid & 3) * 8;
    const ushort* Ag = Ab + (size_t)(m0 + srow) * 1024 + skq;
    const ushort* Bg = BTb + (size_t)(n0 + srow) * 1024 + skq;
    short8 ra = *(const short8*)Ag;
    short8 rb = *(const short8*)Bg;
    float4v acc00 = {0,0,0,0}, acc01 = {0,0,0,0}, acc10 = {0,0,0,0}, acc11 = {0,0,0,0};
    for (int kt = 0; kt < 32; kt++) {
        const int cb = kt & 1;
        *(short8*)&sA[cb][srow][skq] = ra;
        *(short8*)&sB[cb][srow][skq] = rb;
        __syncthreads();
        if (kt + 1 < 32) {
            ra = *(const short8*)(Ag + (kt + 1) * 32);
            rb = *(const short8*)(Bg + (kt + 1) * 32);
        }
        short8 a0 = *(const short8*)&sA[cb][wm * 32 + l16][quad * 8];
        short8 a1 = *(const short8*)&sA[cb][wm * 32 + 16 + l16][quad * 8];
        short8 b0 = *(const short8*)&sB[cb][wn * 32 + l16][quad * 8];
        short8 b1 = *(const short8*)&sB[cb][wn * 32 + 16 + l16][quad * 8];
        acc00 = __builtin_amdgcn_mfma_f32_16x16x32_bf16(a0, b0, acc00, 0, 0, 0);
        acc01 = __builtin_amdgcn_mfma_f32_16x16x32_bf16(a0, b1, acc01, 0, 0, 0);
        acc10 = __builtin_amdgcn_mfma_f32_16x16x32_bf16(a1, b0, acc10, 0, 0, 0);
        acc11 = __builtin_amdgcn_mfma_f32_16x16x32_bf16(a1, b1, acc11, 0, 0, 0);
    }
    const bool sig = (n0 >= 1536);
    const int colb = n0 + wn * 32 + l16;
    const int rowb = m0 + wm * 32 + quad * 4;
    #pragma unroll
    for (int r2 = 0; r2 < 4; r2++) {
        float v00 = acc00[r2], v01 = acc01[r2], v10 = acc10[r2], v11 = acc11[r2];
        if (sig) {
            v00 = 1.0f / (1.0f + expf(-v00));
            v01 = 1.0f / (1.0f + expf(-v01));
            v10 = 1.0f / (1.0f + expf(-v10));
            v11 = 1.0f / (1.0f + expf(-v11));
        }
        proj[(size_t)(rowb + r2) * NPROJ + colb] = v00;
        proj[(size_t)(rowb + r2) * NPROJ + colb + 16] = v01;
        proj[(size_t)(rowb + 16 + r2) * NPROJ + colb] = v10;
        proj[(size_t)(rowb + 16 + r2) * NPROJ + colb + 16] = v11;
    }
}

// ---------------- DPP butterfly add ----------------------------------------------------
template<int CTRL>
__device__ __forceinline__ float dpp_add(float x) {
    int xi = __float_as_int(x);
    int yi = __builtin_amdgcn_update_dpp(xi, xi, CTRL, 0xF, 0xF, false);
    return x + __int_as_float(yi);
}

// ---------------- Kernel 3: scan (packed fp32, hoisted kq, gate+atomic output) ---------
// grid 512 = b(2) x hr(64) x s(4); block 256: vl = tid>>4 (16 v), kl = tid&15 (4 k each)
__global__ __launch_bounds__(256, 2) void scan_kernel(const float* __restrict__ proj,
        const float* __restrict__ cosw, const float* __restrict__ sinw,
        const float* __restrict__ rho, const float* __restrict__ modew,
        float* __restrict__ Acomb)
{
    __shared__ float qk[2][CH][128];    // per t: [0..63]=q, [64..127]=k
    __shared__ float vbuf[2][CH][16];
    __shared__ float gbuf[2][CH][16];   // gate slice
    __shared__ float sc4[2][CH][4];     // [0]=beta [1]=tg [2]=kq

    const int bi = blockIdx.x;
    const int s  = bi & 3;
    const int hr = (bi >> 2) & 63;
    const int b  = bi >> 8;
    const int h = hr >> 3, r = hr & 7;
    const int tid = threadIdx.x;
    const int vl = tid >> 4;
    const int kl = tid & 15;

    float2v cw0, cw1, sw0, sw1;
    cw0.x = cosw[hr * 64 + kl * 4 + 0]; cw0.y = cosw[hr * 64 + kl * 4 + 1];
    cw1.x = cosw[hr * 64 + kl * 4 + 2]; cw1.y = cosw[hr * 64 + kl * 4 + 3];
    sw0.x = sinw[hr * 64 + kl * 4 + 0]; sw0.y = sinw[hr * 64 + kl * 4 + 1];
    sw1.x = sinw[hr * 64 + kl * 4 + 2]; sw1.y = sinw[hr * 64 + kl * 4 + 3];
    const float rho_hr = rho[hr];
    const float mw = modew[hr];
    float2v sr0 = {0,0}, sr1 = {0,0}, si0 = {0,0}, si1 = {0,0};

    const float* pb = proj + (size_t)b * T_ * NPROJ;
    const int qbase = h * 64;
    const int kbase = 512 + h * 64;
    const int vbase = 1024 + h * 64 + s * 16;
    const int gbase = 1664 + h * 64 + s * 16;
    const int boff  = 1536 + h * 8 + r;
    const int goff  = 1600 + h * 8 + r;

    auto stage = [&](int t0, int nb) {
        #pragma unroll
        for (int rep = 0; rep < 4; rep++) {
            int idx = rep * 256 + tid;
            int t = idx >> 5, sub = idx & 31;
            const float* row = pb + (size_t)(t0 + t) * NPROJ;
            float4 val = *(const float4*)(row + (sub < 16 ? qbase + sub * 4
                                                          : kbase + (sub - 16) * 4));
            *(float4*)&qk[nb][t][sub * 4] = val;
        }
        if (tid < 128) {
            int t = tid >> 2, sub = tid & 3;
            *(float4*)&vbuf[nb][t][sub * 4] =
                *(const float4*)(pb + (size_t)(t0 + t) * NPROJ + vbase + sub * 4);
        } else {
            int t = (tid - 128) >> 2, sub = tid & 3;
            *(float4*)&gbuf[nb][t][sub * 4] =
                *(const float4*)(pb + (size_t)(t0 + t) * NPROJ + gbase + sub * 4);
        }
        if (tid < CH)            sc4[nb][tid][0]      = pb[(size_t)(t0 + tid) * NPROJ + boff];
        else if (tid < 2 * CH)   sc4[nb][tid - CH][1] = pb[(size_t)(t0 + tid - CH) * NPROJ + goff];
    };

    stage(0, 0);
    __syncthreads();

    float* dst = Acomb + ((size_t)b * 128) * 512 + h * 64 + s * 16 + vl;

    for (int c = 0; c < T_ / CH; c++) {
        const int cb = c & 1;
        // hoisted kq_t for this chunk: 32 t x 8 lanes x 8 elems
        {
            int t = tid >> 3, j = tid & 7;
            float4 ka = *(const float4*)&qk[cb][t][64 + j * 8];
            float4 kb4 = *(const float4*)&qk[cb][t][64 + j * 8 + 4];
            float4 qa = *(const float4*)&qk[cb][t][j * 8];
            float4 qb4 = *(const float4*)&qk[cb][t][j * 8 + 4];
            float p = ka.x * qa.x + ka.y * qa.y + ka.z * qa.z + ka.w * qa.w
                    + kb4.x * qb4.x + kb4.y * qb4.y + kb4.z * qb4.z + kb4.w * qb4.w;
            p = dpp_add<0xB1>(p);
            p = dpp_add<0x4E>(p);
            p = dpp_add<0x141>(p);
            if (j == 0) sc4[cb][t][2] = p;
        }
        __syncthreads();
        if (c + 1 < T_ / CH) stage((c + 1) * CH, (c + 1) & 1);

        #pragma unroll 4
        for (int t = 0; t < CH; t++) {
            float4 kf = *(const float4*)&qk[cb][t][64 + kl * 4];
            float4 qf = *(const float4*)&qk[cb][t][kl * 4];
            float4 sv = *(const float4*)&sc4[cb][t][0];   // beta, tg, kq
            const float vv = vbuf[cb][t][vl];
            const float gate = gbuf[cb][t][vl];

            const float decay = sv.y * rho_hr;
            float2v k0; k0.x = kf.x; k0.y = kf.y;
            float2v k1; k1.x = kf.z; k1.y = kf.w;
            float2v q0; q0.x = qf.x; q0.y = qf.y;
            float2v q1; q1.x = qf.z; q1.y = qf.w;

            float2v t1 = cw0 * sr0 - sw0 * si0;
            float2v u1 = sw0 * sr0 + cw0 * si0;
            float2v t2 = cw1 * sr1 - sw1 * si1;
            float2v u2 = sw1 * sr1 + cw1 * si1;
            float2v d2; d2.x = decay; d2.y = decay;
            float2v rr0 = d2 * t1, rr1 = d2 * t2;
            si0 = d2 * u1; si1 = d2 * u2;

            float2v pk2 = rr0 * k0 + rr1 * k1;
            float2v pq2 = rr0 * q0 + rr1 * q1;
            float pk = pk2.x + pk2.y;
            float pq = pq2.x + pq2.y;
            pk = dpp_add<0xB1>(pk);  pq = dpp_add<0xB1>(pq);
            pk = dpp_add<0x4E>(pk);  pq = dpp_add<0x4E>(pq);
            pk = dpp_add<0x141>(pk); pq = dpp_add<0x141>(pq);
            pk = dpp_add<0x140>(pk); pq = dpp_add<0x140>(pq);

            const float sc = sv.x * (vv - pk);
            float2v sc2; sc2.x = sc; sc2.y = sc;
            sr0 = rr0 + sc2 * k0;
            sr1 = rr1 + sc2 * k1;
            const float rp = pq + sc * sv.z;   // = sum(sr_new * q)
            if (kl == 0) atomicAdd(dst + (size_t)(c * CH + t) * 512, mw * rp * gate);
        }
        __syncthreads();
    }
}

// ---------------- Kernel 4: output GEMM, A = fp32 Acomb converted inline ---------------
__global__ __launch_bounds__(256, 2) void out_mfma(const float* __restrict__ Af,
        const ushort* __restrict__ BTb, float* __restrict__ C)
{
    __shared__ ushort sA[2][64][40];
    __shared__ ushort sB[2][64][40];
    const int n0 = blockIdx.x * 64, m0 = blockIdx.y * 64;
    const int tid = threadIdx.x;
    const int lane = tid & 63, w = tid >> 6;
    const int wm = w & 1, wn = w >> 1;
    const int l16 = lane & 15, quad = lane >> 4;
    const int srow = tid >> 2, skq = (tid & 3) * 8;
    const float* Ag = Af + (size_t)(m0 + srow) * 512 + skq;
    const ushort* Bg = BTb + (size_t)(n0 + srow) * 512 + skq;
    float4 fa0 = *(const float4*)Ag;
    float4 fa1 = *(const float4*)(Ag + 4);
    short8 rb = *(const short8*)Bg;
    float4v acc00 = {0,0,0,0}, acc01 = {0,0,0,0}, acc10 = {0,0,0,0}, acc11 = {0,0,0,0};
    for (int kt = 0; kt < 16; kt++) {
        const int cb = kt & 1;
        short8 ra;
        ra[0]=f2bf(fa0.x); ra[1]=f2bf(fa0.y); ra[2]=f2bf(fa0.z); ra[3]=f2bf(fa0.w);
        ra[4]=f2bf(fa1.x); ra[5]=f2bf(fa1.y); ra[6]=f2bf(fa1.z); ra[7]=f2bf(fa1.w);
        *(short8*)&sA[cb][srow][skq] = ra;
        *(short8*)&sB[cb][srow][skq] = rb;
        __syncthreads();
        if (kt + 1 < 16) {
            fa0 = *(const float4*)(Ag + (kt + 1) * 32);
            fa1 = *(const float4*)(Ag + (kt + 1) * 32 + 4);
            rb = *(const short8*)(Bg + (kt + 1) * 32);
        }
        short8 a0 = *(const short8*)&sA[cb][wm * 32 + l16][quad * 8];
        short8 a1 = *(const short8*)&sA[cb][wm * 32 + 16 + l16][quad * 8];
        short8 b0 = *(const short8*)&sB[cb][wn * 32 + l16][quad * 8];
        short8 b1 = *(const short8*)&sB[cb][wn * 32 + 16 + l16][quad * 8];
        acc00 = __builtin_amdgcn_mfma_f32_16x16x32_bf16(a0, b0, acc00, 0, 0, 0);
        acc01 = __builtin_amdgcn_mfma_f32_16x16x32_bf16(a0, b1, acc01, 0, 0, 0);
        acc10 = __builtin_amdgcn_mfma_f32_16x16x32_bf16(a1, b0, acc10, 0, 0, 0);
        acc11 = __builtin_amdgcn_mfma_f32_16x16x32_bf16(a1, b1, acc11, 0, 0, 0);
    }
    const int colb = n0 + wn * 32 + l16;
    const int rowb = m0 + wm * 32 + quad * 4;
    #pragma unroll
    for (int r2 = 0; r2 < 4; r2++) {
        C[(size_t)(rowb + r2) * 1024 + colb] = acc00[r2];
        C[(size_t)(rowb + r2) * 1024 + colb + 16] = acc01[r2];
        C[(size_t)(rowb + 16 + r2) * 1024 + colb] = acc10[r2];
        C[(size_t)(rowb + 16 + r2) * 1024 + colb + 16] = acc11[r2];
    }
}

extern "C" void kernel_launch(void* const* d_in, const int* in_sizes, int n_in,
                              void* d_out, int out_size, void* d_ws, size_t ws_size,
                              hipStream_t stream) {
    const float* x   = (const float*)d_in[0];
    const float* Wq  = (const float*)d_in[1];
    const float* Wk  = (const float*)d_in[2];
    const float* Wv  = (const float*)d_in[3];
    const float* Wb  = (const float*)d_in[4];
    const float* Wtg = (const float*)d_in[5];
    const float* ml  = (const float*)d_in[6];
    const float* ldc = (const float*)d_in[7];
    const float* ols = (const float*)d_in[8];
    const float* Wg  = (const float*)d_in[9];
    const float* Wo  = (const float*)d_in[10];
    float* out = (float*)d_out;

    float* ws = (float*)d_ws;
    float* proj    = ws;                                 // 557056 f
    float* cosw    = proj + 256 * NPROJ;                 // 4096
    float* sinw    = cosw + 4096;                        // 4096
    float* rho     = sinw + 4096;                        // 64
    float* modew   = rho + 64;                           // 64
    ushort* xb     = (ushort*)(modew + 64);              // 262144 us = 131072 f
    ushort* wotb   = (ushort*)((float*)xb + 131072);     // 524288 us = 262144 f
    float*  Acomb  = (float*)wotb + 262144;              // 131072 f
    ushort* wtb    = (ushort*)(Acomb + 131072);          // 2228224 us = 1114112 f

    prep_kernel<<<784, 256, 0, stream>>>(x, Wq, Wk, Wv, Wb, Wtg, Wg, Wo,
                                         ml, ldc, ols, cosw, sinw, rho, modew,
                                         xb, wtb, wotb, Acomb);
    proj_mfma<<<dim3(34, 4), 256, 0, stream>>>(xb, wtb, proj);
    scan_kernel<<<512, 256, 0, stream>>>(proj, cosw, sinw, rho, modew, Acomb);
    out_mfma<<<dim3(16, 4), 256, 0, stream>>>(Acomb, wotb, out);
}